// Round 24
// baseline (5622.335 us; speedup 1.0000x reference)
//
#include <hip/hip_runtime.h>
#include <hip/hip_bf16.h>
#include <stdint.h>

#define H_   12
#define DH_  64
#define D_   768
#define F_   3072
#define CB_  256
#define QS   2304
#define NEGV (-1e9f)
#define LSTR 7077888L   // per-layer bf16 W^T pool stride (elements)

typedef __attribute__((ext_vector_type(8))) short bf16x8;
typedef __attribute__((ext_vector_type(4))) float f32x4;

__device__ __forceinline__ float bf(uint16_t u){ return __uint_as_float(((unsigned)u)<<16); }
__device__ __forceinline__ uint16_t f2b(float f){
  __hip_bfloat16 h = __float2bfloat16(f);
  return *reinterpret_cast<uint16_t*>(&h);
}
__device__ __forceinline__ float gelu_f(float x){
  return 0.5f*x*(1.f + erff(x*0.70710678118654752f));
}
__device__ __forceinline__ void gll16(const uint16_t* g, uint16_t* l){
  __builtin_amdgcn_global_load_lds(
      (const __attribute__((address_space(1))) void*)g,
      (__attribute__((address_space(3))) void*)l, 16, 0, 0);
}

// ---------------- embedding + LN (f32 weights) ----------------
__global__ __launch_bounds__(256) void k_embed_ln(
    const int* __restrict__ ids, const int* __restrict__ tt,
    const float* __restrict__ wemb, const float* __restrict__ pemb,
    const float* __restrict__ temb, const float* __restrict__ ga,
    const float* __restrict__ be, float* __restrict__ h,
    uint16_t* __restrict__ xb, int S)
{
  long row = blockIdx.x;
  int s = (int)(row % S);
  int t = threadIdx.x;
  long id = ids[row]; long ty = tt[row];
  float v[3]; float sum=0.f, sq=0.f;
#pragma unroll
  for (int i=0;i<3;i++){
    int c = t + i*256;
    float x = wemb[id*D_+c] + pemb[(long)(s+2)*D_+c] + temb[ty*D_+c];
    v[i]=x; sum+=x; sq+=x*x;
  }
  __shared__ float rs[4], rq[4];
#pragma unroll
  for (int o=32;o>=1;o>>=1){ sum += __shfl_xor(sum,o); sq += __shfl_xor(sq,o); }
  if ((t&63)==0){ rs[t>>6]=sum; rq[t>>6]=sq; }
  __syncthreads();
  sum = rs[0]+rs[1]+rs[2]+rs[3];
  sq  = rq[0]+rq[1]+rq[2]+rq[3];
  float mu = sum*(1.f/D_);
  float va = fmaxf(sq*(1.f/D_) - mu*mu, 0.f);
  float rr = rsqrtf(va + 1e-5f);
#pragma unroll
  for (int i=0;i<3;i++){
    int c = t + i*256;
    float y = (v[i]-mu)*rr*ga[c] + be[c];
    h[row*D_+c] = y;
    xb[row*D_+c] = f2b(y);
  }
}

// ---------------- residual + LN (add is bf16) ----------------
__global__ __launch_bounds__(256) void k_ln_res(
    const float* __restrict__ hin, const uint16_t* __restrict__ add,
    const float* __restrict__ ga, const float* __restrict__ be, long goff,
    float* __restrict__ hout, uint16_t* __restrict__ xb)
{
  long row = blockIdx.x;
  int t = threadIdx.x;
  float v[3]; float sum=0.f, sq=0.f;
#pragma unroll
  for (int i=0;i<3;i++){
    int c = t + i*256;
    float x = hin[row*D_+c] + bf(add[row*D_+c]);
    v[i]=x; sum+=x; sq+=x*x;
  }
  __shared__ float rs[4], rq[4];
#pragma unroll
  for (int o=32;o>=1;o>>=1){ sum += __shfl_xor(sum,o); sq += __shfl_xor(sq,o); }
  if ((t&63)==0){ rs[t>>6]=sum; rq[t>>6]=sq; }
  __syncthreads();
  sum = rs[0]+rs[1]+rs[2]+rs[3];
  sq  = rq[0]+rq[1]+rq[2]+rq[3];
  float mu = sum*(1.f/D_);
  float va = fmaxf(sq*(1.f/D_) - mu*mu, 0.f);
  float rr = rsqrtf(va + 1e-5f);
#pragma unroll
  for (int i=0;i<3;i++){
    int c = t + i*256;
    float y = (v[i]-mu)*rr*ga[goff+c] + be[goff+c];
    hout[row*D_+c] = y;
    xb[row*D_+c] = f2b(y);
  }
}

// ---- all-layer QKVO transpose+convert: z = layer*4 + which ----------------
__global__ __launch_bounds__(256) void k_convall4(
    const float* __restrict__ W0, const float* __restrict__ W1,
    const float* __restrict__ W2, const float* __restrict__ W3,
    uint16_t* __restrict__ Wt)
{
  int z = blockIdx.z;
  int l = z >> 2, which = z & 3;
  const float* W = (which==0)?W0:((which==1)?W1:((which==2)?W2:W3));
  long woff = (long)l*D_*D_;
  uint16_t* dst = Wt + (long)l*LSTR + (long)which*589824;
  __shared__ float tile[32][33];
  int n0 = blockIdx.x*32, k0 = blockIdx.y*32;
  int tx = threadIdx.x & 31, ty = threadIdx.x >> 5;
#pragma unroll
  for (int i=0;i<4;i++)
    tile[ty*4+i][tx] = W[woff + (long)(k0+ty*4+i)*D_ + n0+tx];
  __syncthreads();
#pragma unroll
  for (int i=0;i<4;i++)
    dst[(long)(n0+ty*4+i)*D_ + k0+tx] = f2b(tile[tx][ty*4+i]);
}

// ---- all-layer FFN transpose+convert: z = layer; generic K,N --------------
__global__ __launch_bounds__(256) void k_convallF(
    const float* __restrict__ W, long wstride, uint16_t* __restrict__ Wt,
    long toff, int K, int N)
{
  int l = blockIdx.z;
  long woff = (long)l*wstride;
  uint16_t* dst = Wt + (long)l*LSTR + toff;
  __shared__ float tile[32][33];
  int n0 = blockIdx.x*32, k0 = blockIdx.y*32;
  int tx = threadIdx.x & 31, ty = threadIdx.x >> 5;
#pragma unroll
  for (int i=0;i<4;i++)
    tile[ty*4+i][tx] = W[woff + (long)(k0+ty*4+i)*N + n0+tx];
  __syncthreads();
#pragma unroll
  for (int i=0;i<4;i++)
    dst[(long)(n0+ty*4+i)*K + k0+tx] = f2b(tile[tx][ty*4+i]);
}

// ---- GEMM: C = A(bf16)[M,K] @ Bt(bf16)[N,K]^T + bias; BK=64, XOR-swizzled --
template<int WF32, int WBF16, int ACT>   // ACT: 0 none, 2 gelu
__global__ __launch_bounds__(256) void k_gemm3(
    const uint16_t* __restrict__ A, const uint16_t* __restrict__ Bt,
    const float* __restrict__ bias, long boff, float* __restrict__ outF,
    uint16_t* __restrict__ outB, int N, int K)
{
  __shared__ uint16_t a_lds[128*64];
  __shared__ uint16_t b_lds[128*64];
  int t = threadIdx.x;
  int lane = t & 63, w = t >> 6, l15 = lane & 15, g = lane >> 4;
  int wr = w >> 1, wc = w & 1;
  long bm = (long)blockIdx.x * 128, bn = (long)blockIdx.y * 128;

  f32x4 zero = {0.f,0.f,0.f,0.f};
  f32x4 acc[4][4];
#pragma unroll
  for (int m=0;m<4;m++)
#pragma unroll
    for (int n=0;n<4;n++) acc[m][n]=zero;

  int srow8 = lane >> 3;                          // 0..7
  int scol  = (((lane&7) ^ srow8) << 4) >> 1;     // swizzled source col (elems)

  for (int k0=0;k0<K;k0+=64){
    __syncthreads();
#pragma unroll
    for (int i=0;i<4;i++){
      int row = (w*4+i)*8 + srow8;
      gll16(A  + (bm+row)*(long)K + k0 + scol, a_lds + (w*4+i)*512);
      gll16(Bt + (bn+row)*(long)K + k0 + scol, b_lds + (w*4+i)*512);
    }
    __syncthreads();
#pragma unroll
    for (int kk=0;kk<2;kk++){
      bf16x8 af[4], bfr[4];
#pragma unroll
      for (int m=0;m<4;m++){
        int row = wr*64+m*16+l15;
        int colB = (kk*64 + g*16) ^ ((row&7)<<4);
        af[m] = *(const bf16x8*)&a_lds[row*64 + (colB>>1)];
      }
#pragma unroll
      for (int n=0;n<4;n++){
        int row = wc*64+n*16+l15;
        int colB = (kk*64 + g*16) ^ ((row&7)<<4);
        bfr[n] = *(const bf16x8*)&b_lds[row*64 + (colB>>1)];
      }
#pragma unroll
      for (int m=0;m<4;m++)
#pragma unroll
        for (int n=0;n<4;n++)
          acc[m][n] = __builtin_amdgcn_mfma_f32_16x16x32_bf16(af[m], bfr[n], acc[m][n], 0,0,0);
    }
  }

#pragma unroll
  for (int n=0;n<4;n++){
    long col = bn + wc*64 + n*16 + l15;
    float bv = bias[boff + col];
#pragma unroll
    for (int m=0;m<4;m++){
#pragma unroll
      for (int r=0;r<4;r++){
        long row = bm + wr*64 + m*16 + g*4 + r;
        float vv = acc[m][n][r] + bv;
        if (ACT==2) vv = gelu_f(vv);
        if (WF32)  outF[row*N + col] = vv;
        if (WBF16) outB[row*N + col] = f2b(vv);
      }
    }
  }
}

// ---- fused QKV GEMM (BK=64, swizzled): qkv[M][2304], q-seg scaled ---------
__global__ __launch_bounds__(256) void k_gemmqkv(
    const uint16_t* __restrict__ A, const uint16_t* __restrict__ Bt,
    const float* __restrict__ bq, const float* __restrict__ bk,
    const float* __restrict__ bv, long boff, uint16_t* __restrict__ qkv, int K)
{
  __shared__ uint16_t a_lds[128*64];
  __shared__ uint16_t b_lds[128*64];
  int t = threadIdx.x;
  int lane = t & 63, w = t >> 6, l15 = lane & 15, g = lane >> 4;
  int wr = w >> 1, wc = w & 1;
  long bm = (long)blockIdx.x * 128, bn = (long)blockIdx.y * 128;

  f32x4 zero = {0.f,0.f,0.f,0.f};
  f32x4 acc[4][4];
#pragma unroll
  for (int m=0;m<4;m++)
#pragma unroll
    for (int n=0;n<4;n++) acc[m][n]=zero;

  int srow8 = lane >> 3;
  int scol  = (((lane&7) ^ srow8) << 4) >> 1;

  for (int k0=0;k0<K;k0+=64){
    __syncthreads();
#pragma unroll
    for (int i=0;i<4;i++){
      int row = (w*4+i)*8 + srow8;
      gll16(A  + (bm+row)*(long)K + k0 + scol, a_lds + (w*4+i)*512);
      gll16(Bt + (bn+row)*(long)K + k0 + scol, b_lds + (w*4+i)*512);
    }
    __syncthreads();
#pragma unroll
    for (int kk=0;kk<2;kk++){
      bf16x8 af[4], bfr[4];
#pragma unroll
      for (int m=0;m<4;m++){
        int row = wr*64+m*16+l15;
        int colB = (kk*64 + g*16) ^ ((row&7)<<4);
        af[m] = *(const bf16x8*)&a_lds[row*64 + (colB>>1)];
      }
#pragma unroll
      for (int n=0;n<4;n++){
        int row = wc*64+n*16+l15;
        int colB = (kk*64 + g*16) ^ ((row&7)<<4);
        bfr[n] = *(const bf16x8*)&b_lds[row*64 + (colB>>1)];
      }
#pragma unroll
      for (int m=0;m<4;m++)
#pragma unroll
        for (int n=0;n<4;n++)
          acc[m][n] = __builtin_amdgcn_mfma_f32_16x16x32_bf16(af[m], bfr[n], acc[m][n], 0,0,0);
    }
  }

  int seg = (int)(bn / 768);
  const float* bias = (seg==0) ? bq : ((seg==1) ? bk : bv);
  float scl = (seg==0) ? 0.125f : 1.f;
  long segbase = (long)seg*768;
#pragma unroll
  for (int n=0;n<4;n++){
    long col = bn + wc*64 + n*16 + l15;
    float bvv = bias[boff + (col - segbase)];
#pragma unroll
    for (int m=0;m<4;m++){
#pragma unroll
      for (int r=0;r<4;r++){
        long row = bm + wr*64 + m*16 + g*4 + r;
        qkv[row*QS + col] = f2b((acc[m][n][r] + bvv)*scl);
      }
    }
  }
}

// ---- qg GEMV (both batches, 24 blocks) ------------------------------------
__global__ __launch_bounds__(256) void k_qg2(
    const float* __restrict__ h, const float* __restrict__ Wqg,
    const float* __restrict__ bqg, long woff, long boff,
    float* __restrict__ qg, int S)
{
  int n0 = blockIdx.x*32;
  int t = threadIdx.x;
  int nl = t & 31, kg = t >> 5;
  __shared__ float xs[2][D_];
  for (int i=t;i<D_;i+=256){
    xs[0][i] = h[i];
    xs[1][i] = h[(long)S*D_ + i];
  }
  __syncthreads();
  float a0=0.f, a1=0.f;
  for (int k=kg*96; k<kg*96+96; k++){
    float wv = Wqg[woff + (long)k*D_ + n0 + nl];
    a0 += xs[0][k]*wv;
    a1 += xs[1][k]*wv;
  }
  __shared__ float red[8][2][32];
  red[kg][0][nl]=a0; red[kg][1][nl]=a1;
  __syncthreads();
  if (t < 64){
    int b = t>>5, n = t&31;
    float a = 0.f;
#pragma unroll
    for (int k2=0;k2<8;k2++) a += red[k2][b][n];
    qg[(long)b*D_ + n0+n] = (a + bqg[boff+n0+n])*0.125f;
  }
}

// w2t[b][h][k](bf16); rows h>=12 zero.  c2[b,h] = bkg_h . qg_h
__global__ __launch_bounds__(256) void k_w2(
    const float* __restrict__ Wkg, const float* __restrict__ bkg,
    long woff, long boff, const float* __restrict__ qg,
    uint16_t* __restrict__ w2t, float* __restrict__ c2)
{
  int idx = blockIdx.x*256 + threadIdx.x;
  if (idx >= 2*16*D_) return;
  int b = idx/(16*D_); int r = idx%(16*D_); int h = r/D_; int k = r%D_;
  if (h >= H_){ w2t[((long)b*16 + h)*D_ + k] = 0; return; }
  const float* qh = qg + b*D_ + h*DH_;
  const float* wk = Wkg + woff + (long)k*D_ + h*DH_;
  float a = 0.f;
  for (int d=0;d<DH_;d++) a += wk[d]*qh[d];
  w2t[((long)b*16 + h)*D_ + k] = f2b(a);
  if (k==0){
    const float* bk2 = bkg + boff + h*DH_;
    float c = 0.f;
    for (int d=0;d<DH_;d++) c += bk2[d]*qh[d];
    c2[b*H_+h] = c;
  }
}

// sgb via MFMA: sgb[b,h,s] = xb[row,:].w2t[b][h][:] + c2 + maskbias
__global__ __launch_bounds__(256) void k_sg2(
    const uint16_t* __restrict__ xb, const uint16_t* __restrict__ w2t,
    const float* __restrict__ c2, const int* __restrict__ mask,
    float* __restrict__ sgb, int S)
{
  int t = threadIdx.x, lane = t & 63, w = t >> 6, l15 = lane & 15, g = lane >> 4;
  long row0 = (long)blockIdx.x*64 + w*16;
  int b = (int)(row0 / S);
  f32x4 acc = {0.f,0.f,0.f,0.f};
  const uint16_t* arow = xb + (row0 + l15)*D_;
  const uint16_t* brow = w2t + ((long)b*16 + l15)*D_;
  for (int k0=0;k0<D_;k0+=32){
    bf16x8 af  = *(const bf16x8*)(arow + k0 + g*8);
    bf16x8 bfr = *(const bf16x8*)(brow + k0 + g*8);
    acc = __builtin_amdgcn_mfma_f32_16x16x32_bf16(af, bfr, acc, 0,0,0);
  }
  if (l15 < H_){
    float cc = c2[b*H_+l15];
#pragma unroll
    for (int r=0;r<4;r++){
      long rr = row0 + g*4 + r;
      int s = (int)(rr % S);
      float mb = (mask[rr]>0) ? 0.f : NEGV;
      sgb[((long)(b*H_+l15))*S + s] = acc[r] + cc + mb;
    }
  }
}

// ---------------- sliding-window attention ----------------
// grid (hb=24, n=32): adjacent n of same (h,b) are 24 apart -> same XCD
__global__ __launch_bounds__(256) void k_sliding_attn(
    const uint16_t* __restrict__ qkv, const int* __restrict__ mask,
    uint16_t* __restrict__ attn, int S)
{
  int hb = blockIdx.x, n = blockIdx.y;
  int h = hb % H_, b = hb / H_;
  int t = threadIdx.x;
  int lane = t & 63, w = t >> 6, l15 = lane & 15, g = lane >> 4;

  __shared__ uint16_t k_lds[64*72];
  __shared__ uint16_t v_lds[64*72];
  __shared__ uint16_t p_lds[4][32*72];
  __shared__ float kbias[64];
  __shared__ float gcs[4][32];

  int rowbase = n*128 + w*32;
  const long bS = (long)b*S;
  const uint16_t* q = qkv;
  const uint16_t* k = qkv + 768;
  const uint16_t* v = qkv + 1536;

  bf16x8 qf[2][2];
#pragma unroll
  for (int m=0;m<2;m++)
#pragma unroll
    for (int kf=0;kf<2;kf++)
      qf[m][kf] = *(const bf16x8*)&q[(bS + rowbase + m*16 + l15)*QS + h*DH_ + kf*32 + g*8];

  // gc = q . k_row0 (fused)
  bf16x8 k0f[2];
#pragma unroll
  for (int kf=0;kf<2;kf++)
    k0f[kf] = *(const bf16x8*)&k[bS*QS + h*DH_ + kf*32 + g*8];
#pragma unroll
  for (int m=0;m<2;m++){
    float d = 0.f;
#pragma unroll
    for (int kf=0;kf<2;kf++){
      const uint16_t* qa = (const uint16_t*)&qf[m][kf];
      const uint16_t* ka = (const uint16_t*)&k0f[kf];
#pragma unroll
      for (int j=0;j<8;j++) d += bf(qa[j])*bf(ka[j]);
    }
    d += __shfl_xor(d,16); d += __shfl_xor(d,32);
    if (g==0) gcs[w][m*16+l15] = d;
  }

  float gc[2][4], rmax[2][4], rsum[2][4];
  f32x4 zf = {0.f,0.f,0.f,0.f};
  f32x4 oacc[2][4];
#pragma unroll
  for (int m=0;m<2;m++){
#pragma unroll
    for (int r=0;r<4;r++){
      gc[m][r] = gcs[w][m*16+g*4+r];
      rmax[m][r] = gc[m][r];
      rsum[m][r] = 1.f;
    }
#pragma unroll
    for (int nd=0;nd<4;nd++) oacc[m][nd] = zf;
  }

  int skk = t>>2, sq4 = t&3;

  for (int c=0;c<10;c++){
    __syncthreads();
    {
      int praw = n*128 - 256 + c*64 + skk;
      bool valid = (praw>=1) && (praw<S) && (mask[bS+praw]>0);
      int4 z = {0,0,0,0}; int4 d0=z,d1=z,e0=z,e1=z;
      if (valid){
        const int4* ks = (const int4*)&k[(bS+praw)*QS + h*DH_ + sq4*16];
        d0=ks[0]; d1=ks[1];
        const int4* vs = (const int4*)&v[(bS+praw)*QS + h*DH_ + sq4*16];
        e0=vs[0]; e1=vs[1];
      }
      *(int4*)&k_lds[skk*72 + sq4*16]     = d0;
      *(int4*)&k_lds[skk*72 + sq4*16 + 8] = d1;
      const uint16_t* ev0 = (const uint16_t*)&e0;
      const uint16_t* ev1 = (const uint16_t*)&e1;
#pragma unroll
      for (int i=0;i<8;i++) v_lds[(sq4*16+i)*72 + skk]   = ev0[i];
#pragma unroll
      for (int i=0;i<8;i++) v_lds[(sq4*16+8+i)*72 + skk] = ev1[i];
      if (sq4==0) kbias[skk] = valid ? 0.f : NEGV;
    }
    __syncthreads();

    if (c*64+63 >= w*32 && c*64 <= w*32 + 543){
#pragma unroll
      for (int m=0;m<2;m++){
        float sval[4][4];
#pragma unroll
        for (int nf=0;nf<4;nf++){
          f32x4 sacc = {0.f,0.f,0.f,0.f};
#pragma unroll
          for (int kf=0;kf<2;kf++){
            bf16x8 kfr = *(const bf16x8*)&k_lds[(nf*16+l15)*72 + kf*32 + g*8];
            sacc = __builtin_amdgcn_mfma_f32_16x16x32_bf16(qf[m][kf], kfr, sacc, 0,0,0);
          }
          int koff = c*64 + nf*16 + l15;
          float cb = kbias[nf*16+l15];
#pragma unroll
          for (int r=0;r<4;r++){
            int rib = w*32 + m*16 + g*4 + r;
            bool ok = (koff >= rib) && (koff <= rib + 512);
            sval[nf][r] = ok ? (sacc[r] + cb) : NEGV;
          }
        }
        float bm4[4];
#pragma unroll
        for (int r=0;r<4;r++){
          float bm = fmaxf(fmaxf(sval[0][r],sval[1][r]),fmaxf(sval[2][r],sval[3][r]));
          bm = fmaxf(bm, __shfl_xor(bm,1));
          bm = fmaxf(bm, __shfl_xor(bm,2));
          bm = fmaxf(bm, __shfl_xor(bm,4));
          bm = fmaxf(bm, __shfl_xor(bm,8));
          bm4[r] = bm;
        }
        float mx = 0.f;
#pragma unroll
        for (int r=0;r<4;r++) mx = fmaxf(mx, bm4[r] - rmax[m][r]);
        bool need = __any(mx > 8.0f);
        float nm[4], scl[4], psum[4];
        if (need){
#pragma unroll
          for (int r=0;r<4;r++){
            nm[r]  = fmaxf(rmax[m][r], bm4[r]);
            scl[r] = __expf(rmax[m][r] - nm[r]);
            psum[r]= 0.f;
          }
        } else {
#pragma unroll
          for (int r=0;r<4;r++){ nm[r] = rmax[m][r]; scl[r] = 1.f; psum[r] = 0.f; }
        }
#pragma unroll
        for (int nf=0;nf<4;nf++){
#pragma unroll
          for (int r=0;r<4;r++){
            float pp = __expf(sval[nf][r] - nm[r]);
            psum[r] += pp;
            p_lds[w][(m*16+g*4+r)*72 + nf*16 + l15] = f2b(pp);
          }
        }
#pragma unroll
        for (int r=0;r<4;r++){
          float x = psum[r];
          x += __shfl_xor(x,1); x += __shfl_xor(x,2);
          x += __shfl_xor(x,4); x += __shfl_xor(x,8);
          rsum[m][r] = rsum[m][r]*scl[r] + x;
          rmax[m][r] = nm[r];
        }
        if (need){
#pragma unroll
          for (int nd=0;nd<4;nd++)
#pragma unroll
            for (int r=0;r<4;r++) oacc[m][nd][r] *= scl[r];
        }
      }

#pragma unroll
      for (int m=0;m<2;m++){
        bf16x8 pf[2];
#pragma unroll
        for (int kf=0;kf<2;kf++)
          pf[kf] = *(const bf16x8*)&p_lds[w][(m*16+l15)*72 + kf*32 + g*8];
#pragma unroll
        for (int nd=0;nd<4;nd++){
#pragma unroll
          for (int kf=0;kf<2;kf++){
            bf16x8 vf = *(const bf16x8*)&v_lds[(nd*16+l15)*72 + kf*32 + g*8];
            oacc[m][nd] = __builtin_amdgcn_mfma_f32_16x16x32_bf16(pf[kf], vf, oacc[m][nd], 0,0,0);
          }
        }
      }
    }
  }

  float v0l[4];
#pragma unroll
  for (int nd=0;nd<4;nd++) v0l[nd] = bf(v[bS*QS + h*DH_ + nd*16 + l15]);
#pragma unroll
  for (int m=0;m<2;m++)
#pragma unroll
    for (int r=0;r<4;r++){
      float pg  = __expf(gc[m][r] - rmax[m][r]);
      float inv = 1.f / rsum[m][r];
      long srow = bS + rowbase + m*16 + g*4 + r;
#pragma unroll
      for (int nd=0;nd<4;nd++){
        float ov = (oacc[m][nd][r] + pg*v0l[nd]) * inv;
        attn[srow*D_ + h*DH_ + nd*16 + l15] = f2b(ov);
      }
    }
}

// pbuf[b,h,s] = softmax over s of sgb[b,h,:]
__global__ __launch_bounds__(256) void k_gp(
    const float* __restrict__ sgb, float* __restrict__ pbuf, int S)
{
  int bh = blockIdx.x;
  const float* sp = sgb + (long)bh*S;
  float* pp = pbuf + (long)bh*S;
  int t = threadIdx.x;
  __shared__ float red[4]; __shared__ float bc2[2];
  float m = -3e38f;
  for (int s=t;s<S;s+=256) m = fmaxf(m, sp[s]);
#pragma unroll
  for (int o=32;o>=1;o>>=1) m = fmaxf(m, __shfl_xor(m,o));
  if ((t&63)==0) red[t>>6]=m;
  __syncthreads();
  if (t==0) bc2[0] = fmaxf(fmaxf(red[0],red[1]),fmaxf(red[2],red[3]));
  __syncthreads();
  m = bc2[0];
  float z = 0.f;
  for (int s=t;s<S;s+=256) z += __expf(sp[s]-m);
#pragma unroll
  for (int o=32;o>=1;o>>=1) z += __shfl_xor(z,o);
  if ((t&63)==0) red[t>>6]=z;
  __syncthreads();
  if (t==0) bc2[1] = red[0]+red[1]+red[2]+red[3];
  __syncthreads();
  float invz = 1.f/bc2[1];
  for (int s=t;s<S;s+=256) pp[s] = __expf(sp[s]-m)*invz;
}

// partial yv: pyv[b][sc][h][d] = sum over 128-s chunk of p*x
__global__ __launch_bounds__(256) void k_yvp(
    const uint16_t* __restrict__ xb, const float* __restrict__ pbuf,
    float* __restrict__ pyv, int S)
{
  int dc = blockIdx.x, scn = blockIdx.y, b = blockIdx.z;
  int t = threadIdx.x; int dt = t & 127; int half = t >> 7;
  int d = dc*128 + dt;
  int s0 = scn*128;
  const long bS = (long)b*S;
  __shared__ float pch[H_][128];
  for (int i=t;i<H_*128;i+=256){
    int hh = i >> 7, sj = i & 127;
    pch[hh][sj] = pbuf[((long)(b*H_+hh))*S + s0 + sj];
  }
  __syncthreads();
  float acc[H_];
#pragma unroll
  for (int hh=0;hh<H_;hh++) acc[hh]=0.f;
  for (int sj=half; sj<128; sj+=2){
    float xv = bf(xb[(bS + s0 + sj)*D_ + d]);
#pragma unroll
    for (int hh=0;hh<H_;hh++) acc[hh] += pch[hh][sj]*xv;
  }
  __shared__ float red[H_][128];
  if (half==1){
#pragma unroll
    for (int hh=0;hh<H_;hh++) red[hh][dt] = acc[hh];
  }
  __syncthreads();
  if (half==0){
#pragma unroll
    for (int hh=0;hh<H_;hh++)
      pyv[(((long)b*32 + scn)*H_ + hh)*D_ + d] = acc[hh] + red[hh][dt];
  }
}

// fused: yv[b,h,:] = sum_sc pyv, then og row0 = yv @ Wvg[:,h*64+d] + bvg
__global__ __launch_bounds__(256) void k_og2(
    const float* __restrict__ pyv, const float* __restrict__ Wvg,
    const float* __restrict__ bvg, long woff, long boff,
    uint16_t* __restrict__ attn, int S)
{
  int bh = blockIdx.x; int h = bh % H_, b = bh / H_;
  int t = threadIdx.x;
  __shared__ float yv[D_];
  for (int d=t; d<D_; d+=256){
    float a = 0.f;
    for (int sc=0; sc<32; sc++)
      a += pyv[(((long)b*32 + sc)*H_ + h)*D_ + d];
    yv[d] = a;
  }
  __syncthreads();
  int d = t & 63, ks = t >> 6;
  float og = 0.f;
  for (int k=ks;k<D_;k+=4) og += yv[k]*Wvg[woff+(long)k*D_ + h*DH_ + d];
  __shared__ float pr[4][64];
  pr[ks][d] = og;
  __syncthreads();
  if (ks==0){
    float o = pr[0][d]+pr[1][d]+pr[2][d]+pr[3][d] + bvg[boff+h*DH_+d];
    attn[((long)b*S)*D_ + h*DH_ + d] = f2b(o);
  }
}

// ---- cls GEMV (both batches, 24 blocks) -----------------------------------
__global__ __launch_bounds__(256) void k_cls2(
    const float* __restrict__ h, const float* __restrict__ Wc,
    const float* __restrict__ bc, float* __restrict__ tcls, int S)
{
  int n0 = blockIdx.x*32;
  int t = threadIdx.x;
  int nl = t & 31, kg = t >> 5;
  __shared__ float xs[2][D_];
  for (int i=t;i<D_;i+=256){
    xs[0][i] = h[i];
    xs[1][i] = h[(long)S*D_ + i];
  }
  __syncthreads();
  float a0=0.f, a1=0.f;
  for (int k=kg*96; k<kg*96+96; k++){
    float wv = Wc[(long)k*D_ + n0 + nl];
    a0 += xs[0][k]*wv;
    a1 += xs[1][k]*wv;
  }
  __shared__ float red[8][2][32];
  red[kg][0][nl]=a0; red[kg][1][nl]=a1;
  __syncthreads();
  if (t < 64){
    int b = t>>5, n = t&31;
    float a = 0.f;
#pragma unroll
    for (int k2=0;k2<8;k2++) a += red[k2][b][n];
    tcls[(long)b*D_ + n0+n] = tanhf(a + bc[n0+n]);
  }
}

__global__ void k_head(const float* __restrict__ tcls, const float* __restrict__ Wp,
                       const float* __restrict__ bp, float* __restrict__ out)
{
  int t = threadIdx.x;
  if (t < 20){
    int b = t/10, j = t%10;
    float a = bp[j];
    for (int k=0;k<D_;k++) a += tcls[b*D_+k]*Wp[k*10+j];
    out[t] = a;
  }
}

extern "C" void kernel_launch(void* const* d_in, const int* in_sizes, int n_in,
                              void* d_out, int out_size, void* d_ws, size_t ws_size,
                              hipStream_t stream)
{
  const int B=2, S=4096, L=12;
  const long BS = (long)B*S;

  const int* ids  = (const int*)d_in[0];
  const int* mask = (const int*)d_in[1];
  const int* tt   = (const int*)d_in[2];
  const float* wemb = (const float*)d_in[3];
  const float* pemb = (const float*)d_in[4];
  const float* temb = (const float*)d_in[5];
  const float* lneg = (const float*)d_in[6];
  const float* lneb = (const float*)d_in[7];
  const float* Wq  = (const float*)d_in[8];
  const float* bq  = (const float*)d_in[9];
  const float* Wk  = (const float*)d_in[10];
  const float* bk  = (const float*)d_in[11];
  const float* Wv  = (const float*)d_in[12];
  const float* bv  = (const float*)d_in[13];
  const float* Wqg = (const float*)d_in[14];
  const float* bqg = (const float*)d_in[15];
  const float* Wkg = (const float*)d_in[16];
  const float* bkg = (const float*)d_in[17];
  const float* Wvg = (const float*)d_in[18];
  const float* bvg = (const float*)d_in[19];
  const float* Wo  = (const float*)d_in[20];
  const float* bo  = (const float*)d_in[21];
  const float* ln1g= (const float*)d_in[22];
  const float* ln1b= (const float*)d_in[23];
  const float* Wf1 = (const float*)d_in[24];
  const float* bf1 = (const float*)d_in[25];
  const float* Wf2 = (const float*)d_in[26];
  const float* bf2 = (const float*)d_in[27];
  const float* ln2g= (const float*)d_in[28];
  const float* ln2b= (const float*)d_in[29];
  const float* Wc  = (const float*)d_in[30];
  const float* bc  = (const float*)d_in[31];
  const float* Wp  = (const float*)d_in[32];
  const float* bp  = (const float*)d_in[33];
  (void)in_sizes; (void)n_in; (void)out_size; (void)ws_size;

  char* p = (char*)d_ws;
  auto carve = [&](size_t bytes)->void*{
    void* r = (void*)p; p += (bytes + 255) & ~(size_t)255; return r;
  };
  float*    qg   = (float*)   carve((long)B*D_*4);
  uint16_t* w2t  = (uint16_t*)carve((long)B*16*D_*2);
  float*    c2   = (float*)   carve((long)B*H_*4);
  float*    tcls = (float*)   carve((long)B*D_*4);
  float*    pyv  = (float*)   carve((long)B*32*H_*D_*4);
  float*    sgb  = (float*)   carve((long)B*H_*S*4);
  float*    pbuf = (float*)   carve((long)B*H_*S*4);
  float*    h    = (float*)   carve(BS*D_*4);
  uint16_t* xb   = (uint16_t*)carve(BS*D_*2);
  uint16_t* qkv  = (uint16_t*)carve(BS*(long)QS*2);
  uint16_t* attn = (uint16_t*)carve(BS*D_*2);
  uint16_t* addb = (uint16_t*)carve(BS*D_*2);
  uint16_t* mid  = (uint16_t*)carve(BS*(long)F_*2);
  uint16_t* wtb  = (uint16_t*)carve((long)L*LSTR*2);   // all-layer bf16 W^T pool

  const long OO=1769472, OF1=2359296, OF2=4718592;

  // all-layer weight conversion upfront (3 launches instead of 36)
  k_convall4<<<dim3(24,24,48),256,0,stream>>>(Wq, Wk, Wv, Wo, wtb);
  k_convallF<<<dim3(96,24,12),256,0,stream>>>(Wf1, (long)D_*F_, wtb, OF1, D_, F_);
  k_convallF<<<dim3(24,96,12),256,0,stream>>>(Wf2, (long)D_*F_, wtb, OF2, F_, D_);

  k_embed_ln<<<dim3((unsigned)BS),256,0,stream>>>(ids, tt, wemb, pemb, temb, lneg, lneb, h, xb, S);

  dim3 gQKV(64,18), gO(64,6), gF1(64,24), gF2(64,6);
  for (int l=0;l<L;l++){
    const long wD2 = (long)l*D_*D_, bD = (long)l*D_;
    const long bF = (long)l*F_;
    uint16_t* wl = wtb + (long)l*LSTR;

    k_gemmqkv<<<gQKV,256,0,stream>>>(xb, wl, bq, bk, bv, bD, qkv, D_);
    k_qg2<<<24,256,0,stream>>>(h, Wqg, bqg, wD2, bD, qg, S);
    k_w2<<<96,256,0,stream>>>(Wkg, bkg, wD2, bD, qg, w2t, c2);
    k_sg2<<<(unsigned)(BS/64),256,0,stream>>>(xb, w2t, c2, mask, sgb, S);
    k_sliding_attn<<<dim3(24,32),256,0,stream>>>(qkv, mask, attn, S);
    k_gp<<<B*H_,256,0,stream>>>(sgb, pbuf, S);
    k_yvp<<<dim3(6,32,B),256,0,stream>>>(xb, pbuf, pyv, S);
    k_og2<<<B*H_,256,0,stream>>>(pyv, Wvg, bvg, wD2, bD, attn, S);
    k_gemm3<0,1,0><<<gO,256,0,stream>>>(attn, wl+OO, bo, bD, nullptr, addb, D_, D_);
    k_ln_res<<<dim3((unsigned)BS),256,0,stream>>>(h, addb, ln1g, ln1b, bD, h, xb);
    k_gemm3<0,1,2><<<gF1,256,0,stream>>>(xb, wl+OF1, bf1, bF, nullptr, mid, F_, D_);
    k_gemm3<0,1,0><<<gF2,256,0,stream>>>(mid, wl+OF2, bf2, bD, nullptr, addb, D_, F_);
    k_ln_res<<<dim3((unsigned)BS),256,0,stream>>>(h, addb, ln2g, ln2b, bD, h, xb);
  }

  k_cls2<<<24,256,0,stream>>>(h, Wc, bc, tcls, S);
  k_head<<<1,64,0,stream>>>(tcls, Wp, bp, (float*)d_out);
}

// Round 25
// 5044.251 us; speedup vs baseline: 1.1146x; 1.1146x over previous
//
#include <hip/hip_runtime.h>
#include <hip/hip_bf16.h>
#include <stdint.h>

#define H_   12
#define DH_  64
#define D_   768
#define F_   3072
#define CB_  256
#define QS   2304
#define NEGV (-1e9f)

typedef __attribute__((ext_vector_type(8))) short bf16x8;
typedef __attribute__((ext_vector_type(4))) float f32x4;

__device__ __forceinline__ float bf(uint16_t u){ return __uint_as_float(((unsigned)u)<<16); }
__device__ __forceinline__ uint16_t f2b(float f){
  __hip_bfloat16 h = __float2bfloat16(f);
  return *reinterpret_cast<uint16_t*>(&h);
}
__device__ __forceinline__ float gelu_f(float x){
  return 0.5f*x*(1.f + erff(x*0.70710678118654752f));
}
__device__ __forceinline__ void gll16(const uint16_t* g, uint16_t* l){
  __builtin_amdgcn_global_load_lds(
      (const __attribute__((address_space(1))) void*)g,
      (__attribute__((address_space(3))) void*)l, 16, 0, 0);
}

// ---------------- embedding + LN (f32 weights) ----------------
__global__ __launch_bounds__(256) void k_embed_ln(
    const int* __restrict__ ids, const int* __restrict__ tt,
    const float* __restrict__ wemb, const float* __restrict__ pemb,
    const float* __restrict__ temb, const float* __restrict__ ga,
    const float* __restrict__ be, float* __restrict__ h,
    uint16_t* __restrict__ xb, int S)
{
  long row = blockIdx.x;
  int s = (int)(row % S);
  int t = threadIdx.x;
  long id = ids[row]; long ty = tt[row];
  float v[3]; float sum=0.f, sq=0.f;
#pragma unroll
  for (int i=0;i<3;i++){
    int c = t + i*256;
    float x = wemb[id*D_+c] + pemb[(long)(s+2)*D_+c] + temb[ty*D_+c];
    v[i]=x; sum+=x; sq+=x*x;
  }
  __shared__ float rs[4], rq[4];
#pragma unroll
  for (int o=32;o>=1;o>>=1){ sum += __shfl_xor(sum,o); sq += __shfl_xor(sq,o); }
  if ((t&63)==0){ rs[t>>6]=sum; rq[t>>6]=sq; }
  __syncthreads();
  sum = rs[0]+rs[1]+rs[2]+rs[3];
  sq  = rq[0]+rq[1]+rq[2]+rq[3];
  float mu = sum*(1.f/D_);
  float va = fmaxf(sq*(1.f/D_) - mu*mu, 0.f);
  float rr = rsqrtf(va + 1e-5f);
#pragma unroll
  for (int i=0;i<3;i++){
    int c = t + i*256;
    float y = (v[i]-mu)*rr*ga[c] + be[c];
    h[row*D_+c] = y;
    xb[row*D_+c] = f2b(y);
  }
}

// ---------------- residual + LN (add is bf16) ----------------
__global__ __launch_bounds__(256) void k_ln_res(
    const float* __restrict__ hin, const uint16_t* __restrict__ add,
    const float* __restrict__ ga, const float* __restrict__ be, long goff,
    float* __restrict__ hout, uint16_t* __restrict__ xb)
{
  long row = blockIdx.x;
  int t = threadIdx.x;
  float v[3]; float sum=0.f, sq=0.f;
#pragma unroll
  for (int i=0;i<3;i++){
    int c = t + i*256;
    float x = hin[row*D_+c] + bf(add[row*D_+c]);
    v[i]=x; sum+=x; sq+=x*x;
  }
  __shared__ float rs[4], rq[4];
#pragma unroll
  for (int o=32;o>=1;o>>=1){ sum += __shfl_xor(sum,o); sq += __shfl_xor(sq,o); }
  if ((t&63)==0){ rs[t>>6]=sum; rq[t>>6]=sq; }
  __syncthreads();
  sum = rs[0]+rs[1]+rs[2]+rs[3];
  sq  = rq[0]+rq[1]+rq[2]+rq[3];
  float mu = sum*(1.f/D_);
  float va = fmaxf(sq*(1.f/D_) - mu*mu, 0.f);
  float rr = rsqrtf(va + 1e-5f);
#pragma unroll
  for (int i=0;i<3;i++){
    int c = t + i*256;
    float y = (v[i]-mu)*rr*ga[goff+c] + be[goff+c];
    hout[row*D_+c] = y;
    xb[row*D_+c] = f2b(y);
  }
}

// ---- weight transpose+convert: Wt[n][k](bf16) = W[woff + k*N + n](f32) ----
__global__ __launch_bounds__(256) void k_convw(
    const float* __restrict__ W, long woff, uint16_t* __restrict__ Wt,
    int K, int N)
{
  __shared__ float tile[32][33];
  int n0 = blockIdx.x*32, k0 = blockIdx.y*32;
  int tx = threadIdx.x & 31, ty = threadIdx.x >> 5;
#pragma unroll
  for (int i=0;i<4;i++)
    tile[ty*4+i][tx] = W[woff + (long)(k0+ty*4+i)*N + n0+tx];
  __syncthreads();
#pragma unroll
  for (int i=0;i<4;i++)
    Wt[(long)(n0+ty*4+i)*K + k0+tx] = f2b(tile[tx][ty*4+i]);
}

// 4 DxD weight converts in one launch (z selects source)
__global__ __launch_bounds__(256) void k_convw4(
    const float* __restrict__ W0, const float* __restrict__ W1,
    const float* __restrict__ W2, const float* __restrict__ W3,
    long woff, uint16_t* __restrict__ Wt, long tstride)
{
  const float* W = (blockIdx.z==0)?W0:((blockIdx.z==1)?W1:((blockIdx.z==2)?W2:W3));
  uint16_t* dst = Wt + (long)blockIdx.z*tstride;
  __shared__ float tile[32][33];
  int n0 = blockIdx.x*32, k0 = blockIdx.y*32;
  int tx = threadIdx.x & 31, ty = threadIdx.x >> 5;
#pragma unroll
  for (int i=0;i<4;i++)
    tile[ty*4+i][tx] = W[woff + (long)(k0+ty*4+i)*D_ + n0+tx];
  __syncthreads();
#pragma unroll
  for (int i=0;i<4;i++)
    dst[(long)(n0+ty*4+i)*D_ + k0+tx] = f2b(tile[tx][ty*4+i]);
}

// ---- GEMM: C = A(bf16)[M,K] @ Bt(bf16)[N,K]^T + bias; BK=64, XOR-swizzled --
template<int WF32, int WBF16, int ACT>   // ACT: 0 none, 2 gelu
__global__ __launch_bounds__(256) void k_gemm3(
    const uint16_t* __restrict__ A, const uint16_t* __restrict__ Bt,
    const float* __restrict__ bias, long boff, float* __restrict__ outF,
    uint16_t* __restrict__ outB, int N, int K)
{
  __shared__ uint16_t a_lds[128*64];
  __shared__ uint16_t b_lds[128*64];
  int t = threadIdx.x;
  int lane = t & 63, w = t >> 6, l15 = lane & 15, g = lane >> 4;
  int wr = w >> 1, wc = w & 1;
  long bm = (long)blockIdx.x * 128, bn = (long)blockIdx.y * 128;

  f32x4 zero = {0.f,0.f,0.f,0.f};
  f32x4 acc[4][4];
#pragma unroll
  for (int m=0;m<4;m++)
#pragma unroll
    for (int n=0;n<4;n++) acc[m][n]=zero;

  int srow8 = lane >> 3;                          // 0..7
  int scol  = (((lane&7) ^ srow8) << 4) >> 1;     // swizzled source col (elems)

  for (int k0=0;k0<K;k0+=64){
    __syncthreads();
#pragma unroll
    for (int i=0;i<4;i++){
      int row = (w*4+i)*8 + srow8;
      gll16(A  + (bm+row)*(long)K + k0 + scol, a_lds + (w*4+i)*512);
      gll16(Bt + (bn+row)*(long)K + k0 + scol, b_lds + (w*4+i)*512);
    }
    __syncthreads();
#pragma unroll
    for (int kk=0;kk<2;kk++){
      bf16x8 af[4], bfr[4];
#pragma unroll
      for (int m=0;m<4;m++){
        int row = wr*64+m*16+l15;
        int colB = (kk*64 + g*16) ^ ((row&7)<<4);
        af[m] = *(const bf16x8*)&a_lds[row*64 + (colB>>1)];
      }
#pragma unroll
      for (int n=0;n<4;n++){
        int row = wc*64+n*16+l15;
        int colB = (kk*64 + g*16) ^ ((row&7)<<4);
        bfr[n] = *(const bf16x8*)&b_lds[row*64 + (colB>>1)];
      }
#pragma unroll
      for (int m=0;m<4;m++)
#pragma unroll
        for (int n=0;n<4;n++)
          acc[m][n] = __builtin_amdgcn_mfma_f32_16x16x32_bf16(af[m], bfr[n], acc[m][n], 0,0,0);
    }
  }

#pragma unroll
  for (int n=0;n<4;n++){
    long col = bn + wc*64 + n*16 + l15;
    float bv = bias[boff + col];
#pragma unroll
    for (int m=0;m<4;m++){
#pragma unroll
      for (int r=0;r<4;r++){
        long row = bm + wr*64 + m*16 + g*4 + r;
        float vv = acc[m][n][r] + bv;
        if (ACT==2) vv = gelu_f(vv);
        if (WF32)  outF[row*N + col] = vv;
        if (WBF16) outB[row*N + col] = f2b(vv);
      }
    }
  }
}

// ---- fused QKV GEMM (BK=64, swizzled): qkv[M][2304], q-seg scaled ---------
__global__ __launch_bounds__(256) void k_gemmqkv(
    const uint16_t* __restrict__ A, const uint16_t* __restrict__ Bt,
    const float* __restrict__ bq, const float* __restrict__ bk,
    const float* __restrict__ bv, long boff, uint16_t* __restrict__ qkv, int K)
{
  __shared__ uint16_t a_lds[128*64];
  __shared__ uint16_t b_lds[128*64];
  int t = threadIdx.x;
  int lane = t & 63, w = t >> 6, l15 = lane & 15, g = lane >> 4;
  int wr = w >> 1, wc = w & 1;
  long bm = (long)blockIdx.x * 128, bn = (long)blockIdx.y * 128;

  f32x4 zero = {0.f,0.f,0.f,0.f};
  f32x4 acc[4][4];
#pragma unroll
  for (int m=0;m<4;m++)
#pragma unroll
    for (int n=0;n<4;n++) acc[m][n]=zero;

  int srow8 = lane >> 3;
  int scol  = (((lane&7) ^ srow8) << 4) >> 1;

  for (int k0=0;k0<K;k0+=64){
    __syncthreads();
#pragma unroll
    for (int i=0;i<4;i++){
      int row = (w*4+i)*8 + srow8;
      gll16(A  + (bm+row)*(long)K + k0 + scol, a_lds + (w*4+i)*512);
      gll16(Bt + (bn+row)*(long)K + k0 + scol, b_lds + (w*4+i)*512);
    }
    __syncthreads();
#pragma unroll
    for (int kk=0;kk<2;kk++){
      bf16x8 af[4], bfr[4];
#pragma unroll
      for (int m=0;m<4;m++){
        int row = wr*64+m*16+l15;
        int colB = (kk*64 + g*16) ^ ((row&7)<<4);
        af[m] = *(const bf16x8*)&a_lds[row*64 + (colB>>1)];
      }
#pragma unroll
      for (int n=0;n<4;n++){
        int row = wc*64+n*16+l15;
        int colB = (kk*64 + g*16) ^ ((row&7)<<4);
        bfr[n] = *(const bf16x8*)&b_lds[row*64 + (colB>>1)];
      }
#pragma unroll
      for (int m=0;m<4;m++)
#pragma unroll
        for (int n=0;n<4;n++)
          acc[m][n] = __builtin_amdgcn_mfma_f32_16x16x32_bf16(af[m], bfr[n], acc[m][n], 0,0,0);
    }
  }

  int seg = (int)(bn / 768);
  const float* bias = (seg==0) ? bq : ((seg==1) ? bk : bv);
  float scl = (seg==0) ? 0.125f : 1.f;
  long segbase = (long)seg*768;
#pragma unroll
  for (int n=0;n<4;n++){
    long col = bn + wc*64 + n*16 + l15;
    float bvv = bias[boff + (col - segbase)];
#pragma unroll
    for (int m=0;m<4;m++){
#pragma unroll
      for (int r=0;r<4;r++){
        long row = bm + wr*64 + m*16 + g*4 + r;
        qkv[row*QS + col] = f2b((acc[m][n][r] + bvv)*scl);
      }
    }
  }
}

// ---- qg GEMV (both batches, 24 blocks) ------------------------------------
__global__ __launch_bounds__(256) void k_qg2(
    const float* __restrict__ h, const float* __restrict__ Wqg,
    const float* __restrict__ bqg, long woff, long boff,
    float* __restrict__ qg, int S)
{
  int n0 = blockIdx.x*32;
  int t = threadIdx.x;
  int nl = t & 31, kg = t >> 5;
  __shared__ float xs[2][D_];
  for (int i=t;i<D_;i+=256){
    xs[0][i] = h[i];
    xs[1][i] = h[(long)S*D_ + i];
  }
  __syncthreads();
  float a0=0.f, a1=0.f;
  for (int k=kg*96; k<kg*96+96; k++){
    float wv = Wqg[woff + (long)k*D_ + n0 + nl];
    a0 += xs[0][k]*wv;
    a1 += xs[1][k]*wv;
  }
  __shared__ float red[8][2][32];
  red[kg][0][nl]=a0; red[kg][1][nl]=a1;
  __syncthreads();
  if (t < 64){
    int b = t>>5, n = t&31;
    float a = 0.f;
#pragma unroll
    for (int k2=0;k2<8;k2++) a += red[k2][b][n];
    qg[(long)b*D_ + n0+n] = (a + bqg[boff+n0+n])*0.125f;
  }
}

// w2t[b][h][k](bf16); rows h>=12 zero.  c2[b,h] = bkg_h . qg_h
__global__ __launch_bounds__(256) void k_w2(
    const float* __restrict__ Wkg, const float* __restrict__ bkg,
    long woff, long boff, const float* __restrict__ qg,
    uint16_t* __restrict__ w2t, float* __restrict__ c2)
{
  int idx = blockIdx.x*256 + threadIdx.x;
  if (idx >= 2*16*D_) return;
  int b = idx/(16*D_); int r = idx%(16*D_); int h = r/D_; int k = r%D_;
  if (h >= H_){ w2t[((long)b*16 + h)*D_ + k] = 0; return; }
  const float* qh = qg + b*D_ + h*DH_;
  const float* wk = Wkg + woff + (long)k*D_ + h*DH_;
  float a = 0.f;
  for (int d=0;d<DH_;d++) a += wk[d]*qh[d];
  w2t[((long)b*16 + h)*D_ + k] = f2b(a);
  if (k==0){
    const float* bk2 = bkg + boff + h*DH_;
    float c = 0.f;
    for (int d=0;d<DH_;d++) c += bk2[d]*qh[d];
    c2[b*H_+h] = c;
  }
}

// sgb via MFMA: sgb[b,h,s] = xb[row,:].w2t[b][h][:] + c2 + maskbias
__global__ __launch_bounds__(256) void k_sg2(
    const uint16_t* __restrict__ xb, const uint16_t* __restrict__ w2t,
    const float* __restrict__ c2, const int* __restrict__ mask,
    float* __restrict__ sgb, int S)
{
  int t = threadIdx.x, lane = t & 63, w = t >> 6, l15 = lane & 15, g = lane >> 4;
  long row0 = (long)blockIdx.x*64 + w*16;
  int b = (int)(row0 / S);
  f32x4 acc = {0.f,0.f,0.f,0.f};
  const uint16_t* arow = xb + (row0 + l15)*D_;
  const uint16_t* brow = w2t + ((long)b*16 + l15)*D_;
  for (int k0=0;k0<D_;k0+=32){
    bf16x8 af  = *(const bf16x8*)(arow + k0 + g*8);
    bf16x8 bfr = *(const bf16x8*)(brow + k0 + g*8);
    acc = __builtin_amdgcn_mfma_f32_16x16x32_bf16(af, bfr, acc, 0,0,0);
  }
  if (l15 < H_){
    float cc = c2[b*H_+l15];
#pragma unroll
    for (int r=0;r<4;r++){
      long rr = row0 + g*4 + r;
      int s = (int)(rr % S);
      float mb = (mask[rr]>0) ? 0.f : NEGV;
      sgb[((long)(b*H_+l15))*S + s] = acc[r] + cc + mb;
    }
  }
}

// ---------------- sliding-window attention ----------------
// 64 q-rows/block (wave owns 16), grid (hb=24, n=64): n,n+1 of same (h,b)
// are 24 apart -> same XCD. 9 key-chunks of 64; all waves active each chunk.
__global__ __launch_bounds__(256) void k_sliding_attn(
    const uint16_t* __restrict__ qkv, const int* __restrict__ mask,
    uint16_t* __restrict__ attn, int S)
{
  int hb = blockIdx.x, n = blockIdx.y;
  int h = hb % H_, b = hb / H_;
  int t = threadIdx.x;
  int lane = t & 63, w = t >> 6, l15 = lane & 15, g = lane >> 4;

  __shared__ uint16_t k_lds[64*72];
  __shared__ uint16_t v_lds[64*72];
  __shared__ uint16_t p_lds[4][16*72];
  __shared__ float kbias[64];
  __shared__ float gcs[4][16];

  int rowbase = n*64 + w*16;
  const long bS = (long)b*S;
  const uint16_t* q = qkv;
  const uint16_t* k = qkv + 768;
  const uint16_t* v = qkv + 1536;

  bf16x8 qf[2];
#pragma unroll
  for (int kf=0;kf<2;kf++)
    qf[kf] = *(const bf16x8*)&q[(bS + rowbase + l15)*QS + h*DH_ + kf*32 + g*8];

  // gc = q . k_row0 (fused)
  bf16x8 k0f[2];
#pragma unroll
  for (int kf=0;kf<2;kf++)
    k0f[kf] = *(const bf16x8*)&k[bS*QS + h*DH_ + kf*32 + g*8];
  {
    float d = 0.f;
#pragma unroll
    for (int kf=0;kf<2;kf++){
      const uint16_t* qa = (const uint16_t*)&qf[kf];
      const uint16_t* ka = (const uint16_t*)&k0f[kf];
#pragma unroll
      for (int j=0;j<8;j++) d += bf(qa[j])*bf(ka[j]);
    }
    d += __shfl_xor(d,16); d += __shfl_xor(d,32);
    if (g==0) gcs[w][l15] = d;
  }

  float gc[4], rmax[4], rsum[4];
  f32x4 zf = {0.f,0.f,0.f,0.f};
  f32x4 oacc[4];
#pragma unroll
  for (int r=0;r<4;r++){
    gc[r] = gcs[w][g*4+r];
    rmax[r] = gc[r];
    rsum[r] = 1.f;
  }
#pragma unroll
  for (int nd=0;nd<4;nd++) oacc[nd] = zf;

  int skk = t>>2, sq4 = t&3;

  // keys window: [n*64 - 256, n*64 + 63 + 256] = 9 chunks of 64
  for (int c=0;c<9;c++){
    __syncthreads();
    {
      int praw = n*64 - 256 + c*64 + skk;
      bool valid = (praw>=1) && (praw<S) && (mask[bS+praw]>0);
      int4 z = {0,0,0,0}; int4 d0=z,d1=z,e0=z,e1=z;
      if (valid){
        const int4* ks = (const int4*)&k[(bS+praw)*QS + h*DH_ + sq4*16];
        d0=ks[0]; d1=ks[1];
        const int4* vs = (const int4*)&v[(bS+praw)*QS + h*DH_ + sq4*16];
        e0=vs[0]; e1=vs[1];
      }
      *(int4*)&k_lds[skk*72 + sq4*16]     = d0;
      *(int4*)&k_lds[skk*72 + sq4*16 + 8] = d1;
      const uint16_t* ev0 = (const uint16_t*)&e0;
      const uint16_t* ev1 = (const uint16_t*)&e1;
#pragma unroll
      for (int i=0;i<8;i++) v_lds[(sq4*16+i)*72 + skk]   = ev0[i];
#pragma unroll
      for (int i=0;i<8;i++) v_lds[(sq4*16+8+i)*72 + skk] = ev1[i];
      if (sq4==0) kbias[skk] = valid ? 0.f : NEGV;
    }
    __syncthreads();

    {
      float sval[4][4];
#pragma unroll
      for (int nf=0;nf<4;nf++){
        f32x4 sacc = {0.f,0.f,0.f,0.f};
#pragma unroll
        for (int kf=0;kf<2;kf++){
          bf16x8 kfr = *(const bf16x8*)&k_lds[(nf*16+l15)*72 + kf*32 + g*8];
          sacc = __builtin_amdgcn_mfma_f32_16x16x32_bf16(qf[kf], kfr, sacc, 0,0,0);
        }
        int koff = c*64 + nf*16 + l15;
        float cb = kbias[nf*16+l15];
#pragma unroll
        for (int r=0;r<4;r++){
          int rib = w*16 + g*4 + r;
          bool ok = (koff >= rib) && (koff <= rib + 512);
          sval[nf][r] = ok ? (sacc[r] + cb) : NEGV;
        }
      }
      float bm4[4];
#pragma unroll
      for (int r=0;r<4;r++){
        float bm = fmaxf(fmaxf(sval[0][r],sval[1][r]),fmaxf(sval[2][r],sval[3][r]));
        bm = fmaxf(bm, __shfl_xor(bm,1));
        bm = fmaxf(bm, __shfl_xor(bm,2));
        bm = fmaxf(bm, __shfl_xor(bm,4));
        bm = fmaxf(bm, __shfl_xor(bm,8));
        bm4[r] = bm;
      }
      float mx = 0.f;
#pragma unroll
      for (int r=0;r<4;r++) mx = fmaxf(mx, bm4[r] - rmax[r]);
      bool need = __any(mx > 8.0f);
      float nm[4], scl[4], psum[4];
      if (need){
#pragma unroll
        for (int r=0;r<4;r++){
          nm[r]  = fmaxf(rmax[r], bm4[r]);
          scl[r] = __expf(rmax[r] - nm[r]);
          psum[r]= 0.f;
        }
      } else {
#pragma unroll
        for (int r=0;r<4;r++){ nm[r] = rmax[r]; scl[r] = 1.f; psum[r] = 0.f; }
      }
#pragma unroll
      for (int nf=0;nf<4;nf++){
#pragma unroll
        for (int r=0;r<4;r++){
          float pp = __expf(sval[nf][r] - nm[r]);
          psum[r] += pp;
          p_lds[w][(g*4+r)*72 + nf*16 + l15] = f2b(pp);
        }
      }
#pragma unroll
      for (int r=0;r<4;r++){
        float x = psum[r];
        x += __shfl_xor(x,1); x += __shfl_xor(x,2);
        x += __shfl_xor(x,4); x += __shfl_xor(x,8);
        rsum[r] = rsum[r]*scl[r] + x;
        rmax[r] = nm[r];
      }
      if (need){
#pragma unroll
        for (int nd=0;nd<4;nd++)
#pragma unroll
          for (int r=0;r<4;r++) oacc[nd][r] *= scl[r];
      }

      // PV
      bf16x8 pf[2];
#pragma unroll
      for (int kf=0;kf<2;kf++)
        pf[kf] = *(const bf16x8*)&p_lds[w][l15*72 + kf*32 + g*8];
#pragma unroll
      for (int nd=0;nd<4;nd++){
#pragma unroll
        for (int kf=0;kf<2;kf++){
          bf16x8 vf = *(const bf16x8*)&v_lds[(nd*16+l15)*72 + kf*32 + g*8];
          oacc[nd] = __builtin_amdgcn_mfma_f32_16x16x32_bf16(pf[kf], vf, oacc[nd], 0,0,0);
        }
      }
    }
  }

  float v0l[4];
#pragma unroll
  for (int nd=0;nd<4;nd++) v0l[nd] = bf(v[bS*QS + h*DH_ + nd*16 + l15]);
#pragma unroll
  for (int r=0;r<4;r++){
    float pg  = __expf(gc[r] - rmax[r]);
    float inv = 1.f / rsum[r];
    long srow = bS + rowbase + g*4 + r;
#pragma unroll
    for (int nd=0;nd<4;nd++){
      float ov = (oacc[nd][r] + pg*v0l[nd]) * inv;
      attn[srow*D_ + h*DH_ + nd*16 + l15] = f2b(ov);
    }
  }
}

// pbuf[b,h,s] = softmax over s of sgb[b,h,:]
__global__ __launch_bounds__(256) void k_gp(
    const float* __restrict__ sgb, float* __restrict__ pbuf, int S)
{
  int bh = blockIdx.x;
  const float* sp = sgb + (long)bh*S;
  float* pp = pbuf + (long)bh*S;
  int t = threadIdx.x;
  __shared__ float red[4]; __shared__ float bc2[2];
  float m = -3e38f;
  for (int s=t;s<S;s+=256) m = fmaxf(m, sp[s]);
#pragma unroll
  for (int o=32;o>=1;o>>=1) m = fmaxf(m, __shfl_xor(m,o));
  if ((t&63)==0) red[t>>6]=m;
  __syncthreads();
  if (t==0) bc2[0] = fmaxf(fmaxf(red[0],red[1]),fmaxf(red[2],red[3]));
  __syncthreads();
  m = bc2[0];
  float z = 0.f;
  for (int s=t;s<S;s+=256) z += __expf(sp[s]-m);
#pragma unroll
  for (int o=32;o>=1;o>>=1) z += __shfl_xor(z,o);
  if ((t&63)==0) red[t>>6]=z;
  __syncthreads();
  if (t==0) bc2[1] = red[0]+red[1]+red[2]+red[3];
  __syncthreads();
  float invz = 1.f/bc2[1];
  for (int s=t;s<S;s+=256) pp[s] = __expf(sp[s]-m)*invz;
}

// partial yv: pyv[b][sc][h][d] = sum over 128-s chunk of p*x
__global__ __launch_bounds__(256) void k_yvp(
    const uint16_t* __restrict__ xb, const float* __restrict__ pbuf,
    float* __restrict__ pyv, int S)
{
  int dc = blockIdx.x, scn = blockIdx.y, b = blockIdx.z;
  int t = threadIdx.x; int dt = t & 127; int half = t >> 7;
  int d = dc*128 + dt;
  int s0 = scn*128;
  const long bS = (long)b*S;
  __shared__ float pch[H_][128];
  for (int i=t;i<H_*128;i+=256){
    int hh = i >> 7, sj = i & 127;
    pch[hh][sj] = pbuf[((long)(b*H_+hh))*S + s0 + sj];
  }
  __syncthreads();
  float acc[H_];
#pragma unroll
  for (int hh=0;hh<H_;hh++) acc[hh]=0.f;
  for (int sj=half; sj<128; sj+=2){
    float xv = bf(xb[(bS + s0 + sj)*D_ + d]);
#pragma unroll
    for (int hh=0;hh<H_;hh++) acc[hh] += pch[hh][sj]*xv;
  }
  __shared__ float red[H_][128];
  if (half==1){
#pragma unroll
    for (int hh=0;hh<H_;hh++) red[hh][dt] = acc[hh];
  }
  __syncthreads();
  if (half==0){
#pragma unroll
    for (int hh=0;hh<H_;hh++)
      pyv[(((long)b*32 + scn)*H_ + hh)*D_ + d] = acc[hh] + red[hh][dt];
  }
}

// fused: yv[b,h,:] = sum_sc pyv, then og row0 = yv @ Wvg[:,h*64+d] + bvg
__global__ __launch_bounds__(256) void k_og2(
    const float* __restrict__ pyv, const float* __restrict__ Wvg,
    const float* __restrict__ bvg, long woff, long boff,
    uint16_t* __restrict__ attn, int S)
{
  int bh = blockIdx.x; int h = bh % H_, b = bh / H_;
  int t = threadIdx.x;
  __shared__ float yv[D_];
  for (int d=t; d<D_; d+=256){
    float a = 0.f;
    for (int sc=0; sc<32; sc++)
      a += pyv[(((long)b*32 + sc)*H_ + h)*D_ + d];
    yv[d] = a;
  }
  __syncthreads();
  int d = t & 63, ks = t >> 6;
  float og = 0.f;
  for (int k=ks;k<D_;k+=4) og += yv[k]*Wvg[woff+(long)k*D_ + h*DH_ + d];
  __shared__ float pr[4][64];
  pr[ks][d] = og;
  __syncthreads();
  if (ks==0){
    float o = pr[0][d]+pr[1][d]+pr[2][d]+pr[3][d] + bvg[boff+h*DH_+d];
    attn[((long)b*S)*D_ + h*DH_ + d] = f2b(o);
  }
}

// ---- cls GEMV (both batches, 24 blocks) -----------------------------------
__global__ __launch_bounds__(256) void k_cls2(
    const float* __restrict__ h, const float* __restrict__ Wc,
    const float* __restrict__ bc, float* __restrict__ tcls, int S)
{
  int n0 = blockIdx.x*32;
  int t = threadIdx.x;
  int nl = t & 31, kg = t >> 5;
  __shared__ float xs[2][D_];
  for (int i=t;i<D_;i+=256){
    xs[0][i] = h[i];
    xs[1][i] = h[(long)S*D_ + i];
  }
  __syncthreads();
  float a0=0.f, a1=0.f;
  for (int k=kg*96; k<kg*96+96; k++){
    float wv = Wc[(long)k*D_ + n0 + nl];
    a0 += xs[0][k]*wv;
    a1 += xs[1][k]*wv;
  }
  __shared__ float red[8][2][32];
  red[kg][0][nl]=a0; red[kg][1][nl]=a1;
  __syncthreads();
  if (t < 64){
    int b = t>>5, n = t&31;
    float a = 0.f;
#pragma unroll
    for (int k2=0;k2<8;k2++) a += red[k2][b][n];
    tcls[(long)b*D_ + n0+n] = tanhf(a + bc[n0+n]);
  }
}

__global__ void k_head(const float* __restrict__ tcls, const float* __restrict__ Wp,
                       const float* __restrict__ bp, float* __restrict__ out)
{
  int t = threadIdx.x;
  if (t < 20){
    int b = t/10, j = t%10;
    float a = bp[j];
    for (int k=0;k<D_;k++) a += tcls[b*D_+k]*Wp[k*10+j];
    out[t] = a;
  }
}

extern "C" void kernel_launch(void* const* d_in, const int* in_sizes, int n_in,
                              void* d_out, int out_size, void* d_ws, size_t ws_size,
                              hipStream_t stream)
{
  const int B=2, S=4096, L=12;
  const long BS = (long)B*S;

  const int* ids  = (const int*)d_in[0];
  const int* mask = (const int*)d_in[1];
  const int* tt   = (const int*)d_in[2];
  const float* wemb = (const float*)d_in[3];
  const float* pemb = (const float*)d_in[4];
  const float* temb = (const float*)d_in[5];
  const float* lneg = (const float*)d_in[6];
  const float* lneb = (const float*)d_in[7];
  const float* Wq  = (const float*)d_in[8];
  const float* bq  = (const float*)d_in[9];
  const float* Wk  = (const float*)d_in[10];
  const float* bk  = (const float*)d_in[11];
  const float* Wv  = (const float*)d_in[12];
  const float* bv  = (const float*)d_in[13];
  const float* Wqg = (const float*)d_in[14];
  const float* bqg = (const float*)d_in[15];
  const float* Wkg = (const float*)d_in[16];
  const float* bkg = (const float*)d_in[17];
  const float* Wvg = (const float*)d_in[18];
  const float* bvg = (const float*)d_in[19];
  const float* Wo  = (const float*)d_in[20];
  const float* bo  = (const float*)d_in[21];
  const float* ln1g= (const float*)d_in[22];
  const float* ln1b= (const float*)d_in[23];
  const float* Wf1 = (const float*)d_in[24];
  const float* bf1 = (const float*)d_in[25];
  const float* Wf2 = (const float*)d_in[26];
  const float* bf2 = (const float*)d_in[27];
  const float* ln2g= (const float*)d_in[28];
  const float* ln2b= (const float*)d_in[29];
  const float* Wc  = (const float*)d_in[30];
  const float* bc  = (const float*)d_in[31];
  const float* Wp  = (const float*)d_in[32];
  const float* bp  = (const float*)d_in[33];
  (void)in_sizes; (void)n_in; (void)out_size; (void)ws_size;

  char* p = (char*)d_ws;
  auto carve = [&](size_t bytes)->void*{
    void* r = (void*)p; p += (bytes + 255) & ~(size_t)255; return r;
  };
  float*    qg   = (float*)   carve((long)B*D_*4);
  uint16_t* w2t  = (uint16_t*)carve((long)B*16*D_*2);
  float*    c2   = (float*)   carve((long)B*H_*4);
  float*    tcls = (float*)   carve((long)B*D_*4);
  float*    pyv  = (float*)   carve((long)B*32*H_*D_*4);
  float*    sgb  = (float*)   carve((long)B*H_*S*4);
  float*    pbuf = (float*)   carve((long)B*H_*S*4);
  float*    h    = (float*)   carve(BS*D_*4);
  uint16_t* xb   = (uint16_t*)carve(BS*D_*2);
  uint16_t* qkv  = (uint16_t*)carve(BS*(long)QS*2);
  uint16_t* attn = (uint16_t*)carve(BS*D_*2);
  uint16_t* addb = (uint16_t*)carve(BS*D_*2);
  uint16_t* mid  = (uint16_t*)carve(BS*(long)F_*2);
  uint16_t* wtb  = (uint16_t*)carve((long)7077888*2);   // per-layer bf16 W^T pool

  const long OQ=0, OO=1769472, OF1=2359296, OF2=4718592;

  k_embed_ln<<<dim3((unsigned)BS),256,0,stream>>>(ids, tt, wemb, pemb, temb, lneg, lneb, h, xb, S);

  dim3 gQKV(64,18), gO(64,6), gF1(64,24), gF2(64,6);
  for (int l=0;l<L;l++){
    const long wD2 = (long)l*D_*D_, bD = (long)l*D_;
    const long wF  = (long)l*D_*F_, bF = (long)l*F_;

    k_convw4<<<dim3(24,24,4),256,0,stream>>>(Wq, Wk, Wv, Wo, wD2, wtb, 589824);
    k_convw<<<dim3(96,24),256,0,stream>>>(Wf1, wF, wtb+OF1, D_, F_);
    k_convw<<<dim3(24,96),256,0,stream>>>(Wf2, wF, wtb+OF2, F_, D_);

    k_gemmqkv<<<gQKV,256,0,stream>>>(xb, wtb+OQ, bq, bk, bv, bD, qkv, D_);
    k_qg2<<<24,256,0,stream>>>(h, Wqg, bqg, wD2, bD, qg, S);
    k_w2<<<96,256,0,stream>>>(Wkg, bkg, wD2, bD, qg, w2t, c2);
    k_sg2<<<(unsigned)(BS/64),256,0,stream>>>(xb, w2t, c2, mask, sgb, S);
    k_sliding_attn<<<dim3(24,64),256,0,stream>>>(qkv, mask, attn, S);
    k_gp<<<B*H_,256,0,stream>>>(sgb, pbuf, S);
    k_yvp<<<dim3(6,32,B),256,0,stream>>>(xb, pbuf, pyv, S);
    k_og2<<<B*H_,256,0,stream>>>(pyv, Wvg, bvg, wD2, bD, attn, S);
    k_gemm3<0,1,0><<<gO,256,0,stream>>>(attn, wtb+OO, bo, bD, nullptr, addb, D_, D_);
    k_ln_res<<<dim3((unsigned)BS),256,0,stream>>>(h, addb, ln1g, ln1b, bD, h, xb);
    k_gemm3<0,1,2><<<gF1,256,0,stream>>>(xb, wtb+OF1, bf1, bF, nullptr, mid, F_, D_);
    k_gemm3<0,1,0><<<gF2,256,0,stream>>>(mid, wtb+OF2, bf2, bD, nullptr, addb, D_, F_);
    k_ln_res<<<dim3((unsigned)BS),256,0,stream>>>(h, addb, ln2g, ln2b, bD, h, xb);
  }

  k_cls2<<<24,256,0,stream>>>(h, Wc, bc, tcls, S);
  k_head<<<1,64,0,stream>>>(tcls, Wp, bp, (float*)d_out);
}